// Round 5
// baseline (407.420 us; speedup 1.0000x reference)
//
#include <hip/hip_runtime.h>
#include <math.h>

// GCN 2-layer, pull-based (CSR by dst via counting sort), no float atomics.
// Algebra: segsum commutes with right-matmul, so BOTH matmuls are hoisted:
//   fW1 = feat@W1 (one tiled GEMM over N rows, not per-edge / per-node)
//   h   = relu(segsum(fW1[src]) + b1)        <- layer1: gather + relu only
//   p   = h@W2 (compact per-node, 16 W2 loads) ; out = softmax(segsum(p[src]) + b2)
// R4: rocprof showed the per-node dense1 (64 W1 col loads/node from L1) was
//     ~90us invariant across R2/R3. Hoisting W1 deletes it. All-f32 (absmax
//     headroom restored after R3's 0.0195/0.02 close call).

#define SCAN_B 1024
#define NPB 32   // nodes per block in fw1 GEMM (8 per wave)

__device__ __forceinline__ unsigned short f2bf(float x) {
    unsigned u = __float_as_uint(x);
    unsigned r = (u + 0x7fff + ((u >> 16) & 1)) >> 16;   // RNE
    return (unsigned short)r;
}

// ---------------- CSR build ----------------
__global__ void hist_kernel(const int* __restrict__ dst, int* __restrict__ counts, int E) {
    int e = blockIdx.x * blockDim.x + threadIdx.x;
    if (e < E) atomicAdd(&counts[dst[e]], 1);
}

__global__ void scan_phaseA(const int* __restrict__ counts, int* __restrict__ excl,
                            int* __restrict__ blocksums, int n) {
    __shared__ int lds[SCAN_B];
    int tid = threadIdx.x;
    int i = blockIdx.x * SCAN_B + tid;
    int v = (i < n) ? counts[i] : 0;
    lds[tid] = v;
    __syncthreads();
    for (int off = 1; off < SCAN_B; off <<= 1) {
        int t = (tid >= off) ? lds[tid - off] : 0;
        __syncthreads();
        lds[tid] += t;
        __syncthreads();
    }
    if (i < n) excl[i] = lds[tid] - v;
    if (tid == SCAN_B - 1) blocksums[blockIdx.x] = lds[SCAN_B - 1];
}

__global__ void scan_phaseB(int* blocksums, int nb) {
    __shared__ int lds[SCAN_B];
    int tid = threadIdx.x;
    int v = (tid < nb) ? blocksums[tid] : 0;
    lds[tid] = v;
    __syncthreads();
    for (int off = 1; off < SCAN_B; off <<= 1) {
        int t = (tid >= off) ? lds[tid - off] : 0;
        __syncthreads();
        lds[tid] += t;
        __syncthreads();
    }
    if (tid < nb) blocksums[tid] = lds[tid] - v;
}

__global__ void scan_phaseC(int* __restrict__ offs, const int* __restrict__ blocksums,
                            int* __restrict__ cursor, int n, int E) {
    int i = blockIdx.x * blockDim.x + threadIdx.x;
    if (i < n) {
        int o = offs[i] + blocksums[i / SCAN_B];
        offs[i] = o;
        cursor[i] = o;
    } else if (i == n) {
        offs[n] = E;
    }
}

__global__ void fill_kernel(const int* __restrict__ src, const int* __restrict__ dst,
                            int* __restrict__ cursor, int* __restrict__ ssort, int E) {
    int e = blockIdx.x * blockDim.x + threadIdx.x;
    if (e < E) {
        int pos = atomicAdd(&cursor[dst[e]], 1);
        ssort[pos] = src[e];
    }
}

// ---------------- fW1 = feat @ W1 (tiled GEMM, 8 nodes/wave W1 reuse) ----------------
__global__ __launch_bounds__(256) void fw1_f32_kernel(
    const float4* __restrict__ feat4, const float* __restrict__ W1,
    float* __restrict__ fW1, int n_nodes)
{
    __shared__ float4 lds4[NPB][16];      // 32 rows x 64 f32 = 8KB
    int t = threadIdx.x;
    int base = blockIdx.x * NPB;
#pragma unroll
    for (int it = 0; it < 2; ++it) {
        int flat = it * 256 + t;
        int r = flat >> 4, c = flat & 15;
        int gr = base + r;
        lds4[r][c] = (gr < n_nodes) ? feat4[(size_t)gr * 16 + c]
                                    : make_float4(0.f, 0.f, 0.f, 0.f);
    }
    __syncthreads();
    int lane = t & 63, w = t >> 6;
    float acc[8] = {0.f, 0.f, 0.f, 0.f, 0.f, 0.f, 0.f, 0.f};
#pragma unroll
    for (int k4 = 0; k4 < 16; ++k4) {
        float w0 = W1[(k4 * 4 + 0) * 64 + lane];
        float w1 = W1[(k4 * 4 + 1) * 64 + lane];
        float w2 = W1[(k4 * 4 + 2) * 64 + lane];
        float w3 = W1[(k4 * 4 + 3) * 64 + lane];
#pragma unroll
        for (int i = 0; i < 8; ++i) {
            float4 f = lds4[w * 8 + i][k4];   // LDS broadcast
            acc[i] = fmaf(f.x, w0, fmaf(f.y, w1, fmaf(f.z, w2, fmaf(f.w, w3, acc[i]))));
        }
    }
#pragma unroll
    for (int i = 0; i < 8; ++i) {
        int gr = base + w * 8 + i;
        if (gr < n_nodes) fW1[(size_t)gr * 64 + lane] = acc[i];
    }
}

// bf16-packed variant (ws-size fallback only)
__global__ __launch_bounds__(256) void fw1_bf16_kernel(
    const float4* __restrict__ feat4, const float* __restrict__ W1,
    unsigned* __restrict__ fW1b, int n_nodes)
{
    __shared__ float4 lds4[NPB][16];
    int t = threadIdx.x;
    int base = blockIdx.x * NPB;
#pragma unroll
    for (int it = 0; it < 2; ++it) {
        int flat = it * 256 + t;
        int r = flat >> 4, c = flat & 15;
        int gr = base + r;
        lds4[r][c] = (gr < n_nodes) ? feat4[(size_t)gr * 16 + c]
                                    : make_float4(0.f, 0.f, 0.f, 0.f);
    }
    __syncthreads();
    int lane = t & 63, w = t >> 6;
    float acc[8] = {0.f, 0.f, 0.f, 0.f, 0.f, 0.f, 0.f, 0.f};
#pragma unroll
    for (int k4 = 0; k4 < 16; ++k4) {
        float w0 = W1[(k4 * 4 + 0) * 64 + lane];
        float w1 = W1[(k4 * 4 + 1) * 64 + lane];
        float w2 = W1[(k4 * 4 + 2) * 64 + lane];
        float w3 = W1[(k4 * 4 + 3) * 64 + lane];
#pragma unroll
        for (int i = 0; i < 8; ++i) {
            float4 f = lds4[w * 8 + i][k4];
            acc[i] = fmaf(f.x, w0, fmaf(f.y, w1, fmaf(f.z, w2, fmaf(f.w, w3, acc[i]))));
        }
    }
#pragma unroll
    for (int i = 0; i < 8; ++i) {
        float other = __shfl_xor(acc[i], 1, 64);
        int gr = base + w * 8 + i;
        if (gr < n_nodes && !(lane & 1)) {
            unsigned u = (unsigned)f2bf(acc[i]) | ((unsigned)f2bf(other) << 16);
            fW1b[(size_t)gr * 32 + (lane >> 1)] = u;
        }
    }
}

// ------- shared layer1 tail: b1 + relu + compact dense2 (h@W2 -> p) -------
__device__ __forceinline__ void layer1_tail(float acc, int lane, int node,
                                            const float* __restrict__ b1,
                                            const float* __restrict__ W2,
                                            float* __restrict__ p)
{
    float h = fmaxf(acc + b1[lane], 0.f);
    int j = lane & 15, ks = lane >> 4;
    float pp = 0.f;
#pragma unroll
    for (int i = 0; i < 16; ++i) {
        int kk = ks * 16 + i;
        float hk = __shfl(h, kk, 64);          // broadcast h[kk] from lane kk
        pp = fmaf(hk, W2[kk * 16 + j], pp);
    }
    pp += __shfl_xor(pp, 16, 64);
    pp += __shfl_xor(pp, 32, 64);
    if (ks == 0) p[(size_t)node * 16 + j] = pp;
}

// ---------- layer1 (f32): gather fW1 rows, float2/lane, 2 edges per instr ----------
__global__ __launch_bounds__(256) void layer1_f32_kernel(
    const float2* __restrict__ fW1_2, const int* __restrict__ offs,
    const int* __restrict__ ssort, const float* __restrict__ b1,
    const float* __restrict__ W2, float* __restrict__ p, int n_nodes)
{
    int lane = threadIdx.x & 63;
    int w = threadIdx.x >> 6;
    int node = blockIdx.x * 4 + w;
    if (node >= n_nodes) return;            // no barriers below
    int beg = offs[node], end = offs[node + 1];
    int half = lane >> 5;                   // which edge of the pair
    int sl = lane & 31;                     // col pair -> cols 2sl, 2sl+1
    float ax = 0.f, ay = 0.f;
    int k = beg + half;
    for (; k + 6 < end; k += 8) {           // 8 edges in flight per wave
        int s0 = ssort[k], s1 = ssort[k + 2], s2 = ssort[k + 4], s3 = ssort[k + 6];
        float2 v0 = fW1_2[(size_t)s0 * 32 + sl];
        float2 v1 = fW1_2[(size_t)s1 * 32 + sl];
        float2 v2 = fW1_2[(size_t)s2 * 32 + sl];
        float2 v3 = fW1_2[(size_t)s3 * 32 + sl];
        ax += (v0.x + v1.x) + (v2.x + v3.x);
        ay += (v0.y + v1.y) + (v2.y + v3.y);
    }
    for (; k < end; k += 2) {
        float2 v = fW1_2[(size_t)ssort[k] * 32 + sl];
        ax += v.x;
        ay += v.y;
    }
    ax += __shfl_xor(ax, 32, 64);
    ay += __shfl_xor(ay, 32, 64);
    // redistribute (col-pair layout on 32 lanes) -> one col per lane
    float am = __shfl(ax, lane >> 1, 64);
    float bm = __shfl(ay, lane >> 1, 64);
    float acc = (lane & 1) ? bm : am;
    layer1_tail(acc, lane, node, b1, W2, p);
}

// ---------- layer1 (bf16 fallback): gather packed fW1b rows ----------
__global__ __launch_bounds__(256) void layer1_bf16_kernel(
    const unsigned* __restrict__ fW1b, const int* __restrict__ offs,
    const int* __restrict__ ssort, const float* __restrict__ b1,
    const float* __restrict__ W2, float* __restrict__ p, int n_nodes)
{
    int lane = threadIdx.x & 63;
    int w = threadIdx.x >> 6;
    int node = blockIdx.x * 4 + w;
    if (node >= n_nodes) return;
    int beg = offs[node], end = offs[node + 1];
    int half = lane >> 5;
    int sl = lane & 31;
    float ax = 0.f, ay = 0.f;
    int k = beg + half;
    for (; k + 6 < end; k += 8) {
        int s0 = ssort[k], s1 = ssort[k + 2], s2 = ssort[k + 4], s3 = ssort[k + 6];
        unsigned u0 = fW1b[(size_t)s0 * 32 + sl];
        unsigned u1 = fW1b[(size_t)s1 * 32 + sl];
        unsigned u2 = fW1b[(size_t)s2 * 32 + sl];
        unsigned u3 = fW1b[(size_t)s3 * 32 + sl];
        ax += (__uint_as_float(u0 << 16) + __uint_as_float(u1 << 16))
            + (__uint_as_float(u2 << 16) + __uint_as_float(u3 << 16));
        ay += (__uint_as_float(u0 & 0xffff0000u) + __uint_as_float(u1 & 0xffff0000u))
            + (__uint_as_float(u2 & 0xffff0000u) + __uint_as_float(u3 & 0xffff0000u));
    }
    for (; k < end; k += 2) {
        unsigned u = fW1b[(size_t)ssort[k] * 32 + sl];
        ax += __uint_as_float(u << 16);
        ay += __uint_as_float(u & 0xffff0000u);
    }
    ax += __shfl_xor(ax, 32, 64);
    ay += __shfl_xor(ay, 32, 64);
    float am = __shfl(ax, lane >> 1, 64);
    float bm = __shfl(ay, lane >> 1, 64);
    float acc = (lane & 1) ? bm : am;
    layer1_tail(acc, lane, node, b1, W2, p);
}

// ---------- layer2: wave/node, float2 per lane, 8 edges per load instr ----------
__global__ __launch_bounds__(256) void layer2_kernel(
    const float2* __restrict__ p2, const int* __restrict__ offs,
    const int* __restrict__ ssort, const float* __restrict__ b2,
    float* __restrict__ out, int n_nodes)
{
    int lane = threadIdx.x & 63;
    int w = threadIdx.x >> 6;
    int node = blockIdx.x * 4 + w;
    if (node >= n_nodes) return;
    int slot = lane >> 3;   // edge slot 0..7
    int cp = lane & 7;      // column pair -> cols 2cp, 2cp+1
    int beg = offs[node], end = offs[node + 1];
    float ax = 0.f, ay = 0.f;
    int k = beg + slot;
    for (; k + 8 < end; k += 16) {      // 16 edges in flight
        int s0 = ssort[k], s1 = ssort[k + 8];
        float2 v0 = p2[(size_t)s0 * 8 + cp];
        float2 v1 = p2[(size_t)s1 * 8 + cp];
        ax += v0.x + v1.x;
        ay += v0.y + v1.y;
    }
    for (; k < end; k += 8) {
        float2 v = p2[(size_t)ssort[k] * 8 + cp];
        ax += v.x;
        ay += v.y;
    }
    ax += __shfl_xor(ax, 8, 64);  ay += __shfl_xor(ay, 8, 64);
    ax += __shfl_xor(ax, 16, 64); ay += __shfl_xor(ay, 16, 64);
    ax += __shfl_xor(ax, 32, 64); ay += __shfl_xor(ay, 32, 64);
    float2 bb = ((const float2*)b2)[cp];
    float vx = ax + bb.x, vy = ay + bb.y;
    float m = fmaxf(vx, vy);
    m = fmaxf(m, __shfl_xor(m, 1, 64));
    m = fmaxf(m, __shfl_xor(m, 2, 64));
    m = fmaxf(m, __shfl_xor(m, 4, 64));
    float ex = __expf(vx - m), ey = __expf(vy - m);
    float s = ex + ey;
    s += __shfl_xor(s, 1, 64);
    s += __shfl_xor(s, 2, 64);
    s += __shfl_xor(s, 4, 64);
    if (slot == 0) {
        float inv = 1.f / s;
        float2 o; o.x = ex * inv; o.y = ey * inv;
        ((float2*)out)[(size_t)node * 8 + cp] = o;
    }
}

extern "C" void kernel_launch(void* const* d_in, const int* in_sizes, int n_in,
                              void* d_out, int out_size, void* d_ws, size_t ws_size,
                              hipStream_t stream) {
    const float* feat = (const float*)d_in[0];
    const float* W1   = (const float*)d_in[1];
    const float* b1   = (const float*)d_in[2];
    const float* W2   = (const float*)d_in[3];
    const float* b2   = (const float*)d_in[4];
    const int*   src  = (const int*)d_in[5];
    const int*   dst  = (const int*)d_in[6];

    int N = in_sizes[0] / 64;
    int E = in_sizes[5];

    // f32 layout: p[N*16] | fW1[N*64] | counts[N] | offs[N+1] | cursor[N] | bsums | ssort[E]
    size_t need_f32 = ((size_t)N * 16 + (size_t)N * 64) * 4
                    + ((size_t)N * 3 + 1 + SCAN_B + (size_t)E) * 4;
    bool use_f32 = ws_size >= need_f32;

    float*    p      = (float*)d_ws;
    float*    fW1    = p + (size_t)N * 16;                 // f32 path
    unsigned* fW1b   = (unsigned*)fW1;                     // bf16 path (N*32 u32)
    int* tail = use_f32 ? (int*)(fW1 + (size_t)N * 64)
                        : (int*)(fW1b + (size_t)N * 32);
    int* counts = tail;
    int* offs   = counts + N;
    int* cursor = offs + N + 1;
    int* bsums  = cursor + N;
    int* ssort  = bsums + SCAN_B;
    float* out  = (float*)d_out;

    int nb = (N + SCAN_B - 1) / SCAN_B;

    hipMemsetAsync(counts, 0, (size_t)N * sizeof(int), stream);

    hist_kernel<<<(E + 255) / 256, 256, 0, stream>>>(dst, counts, E);
    if (use_f32) {
        fw1_f32_kernel<<<(N + NPB - 1) / NPB, 256, 0, stream>>>((const float4*)feat, W1, fW1, N);
    } else {
        fw1_bf16_kernel<<<(N + NPB - 1) / NPB, 256, 0, stream>>>((const float4*)feat, W1, fW1b, N);
    }
    scan_phaseA<<<nb, SCAN_B, 0, stream>>>(counts, offs, bsums, N);
    scan_phaseB<<<1, SCAN_B, 0, stream>>>(bsums, nb);
    scan_phaseC<<<(N + 1 + 255) / 256, 256, 0, stream>>>(offs, bsums, cursor, N, E);
    fill_kernel<<<(E + 255) / 256, 256, 0, stream>>>(src, dst, cursor, ssort, E);

    if (use_f32) {
        layer1_f32_kernel<<<(N + 3) / 4, 256, 0, stream>>>((const float2*)fW1, offs, ssort, b1, W2, p, N);
    } else {
        layer1_bf16_kernel<<<(N + 3) / 4, 256, 0, stream>>>(fW1b, offs, ssort, b1, W2, p, N);
    }
    layer2_kernel<<<(N + 3) / 4, 256, 0, stream>>>((const float2*)p, offs, ssort, b2, out, N);
}

// Round 6
// 256.383 us; speedup vs baseline: 1.5891x; 1.5891x over previous
//
#include <hip/hip_runtime.h>
#include <math.h>

// GCN 2-layer, pull-based (CSR by dst via counting sort), no float atomics.
// Algebra: segsum commutes with right-matmul -> both matmuls hoisted:
//   fW1 = feat@W1 (one pass over N rows)
//   h   = relu(segsum(fW1[src]) + b1)
//   p   = h@W2 (compact per-node) ; out = softmax(segsum(p[src]) + b2)
// R5: (a) fw1 rewritten lean (W1 in LDS, wave/node, ~30 VGPR) after R4's
//     256-VGPR spill blowup (132us, 208MB scratch writes);
//     (b) fw1 fused into hist's grid (hist is atomic-latency-bound, machine
//     idle -> fw1 rides free);
//     (c) fill de-atomicized via rank trick (hist's atomicAdd return value
//     is the within-segment rank; fill becomes pure scatter).

#define SCAN_B 1024
#define FW1B   1024   // blocks of the fused grid doing fw1

// ---------------- fused prep: blocks [0,FW1B) do fW1=feat@W1, rest do hist ----------------
__global__ __launch_bounds__(256) void prep_kernel(
    const float* __restrict__ feat, const float* __restrict__ W1,
    float* __restrict__ fW1, const int* __restrict__ dst,
    int* __restrict__ counts, int* __restrict__ rank, int n_nodes, int E)
{
    if ((int)blockIdx.x >= FW1B) {
        // ---- histogram (+rank) part ----
        int e = ((int)blockIdx.x - FW1B) * 256 + threadIdx.x;
        if (e < E) {
            int r = atomicAdd(&counts[dst[e]], 1);
            if (rank) rank[e] = r;
        }
        return;
    }
    // ---- fW1 part: W1 staged in LDS once per block, wave per node ----
    __shared__ float w1s[4096];
    for (int i = threadIdx.x; i < 4096; i += 256) w1s[i] = W1[i];
    __syncthreads();
    int lane = threadIdx.x & 63, w = threadIdx.x >> 6;
    for (int node = (int)blockIdx.x * 4 + w; node < n_nodes; node += FW1B * 4) {
        float r = feat[(size_t)node * 64 + lane];
        float a0 = 0.f, a1 = 0.f;
#pragma unroll
        for (int k = 0; k < 64; k += 2) {
            a0 = fmaf(__shfl(r, k, 64),     w1s[k * 64 + lane],       a0);
            a1 = fmaf(__shfl(r, k + 1, 64), w1s[(k + 1) * 64 + lane], a1);
        }
        fW1[(size_t)node * 64 + lane] = a0 + a1;
    }
}

// ---------------- scan ----------------
__global__ void scan_phaseA(const int* __restrict__ counts, int* __restrict__ excl,
                            int* __restrict__ blocksums, int n) {
    __shared__ int lds[SCAN_B];
    int tid = threadIdx.x;
    int i = blockIdx.x * SCAN_B + tid;
    int v = (i < n) ? counts[i] : 0;
    lds[tid] = v;
    __syncthreads();
    for (int off = 1; off < SCAN_B; off <<= 1) {
        int t = (tid >= off) ? lds[tid - off] : 0;
        __syncthreads();
        lds[tid] += t;
        __syncthreads();
    }
    if (i < n) excl[i] = lds[tid] - v;
    if (tid == SCAN_B - 1) blocksums[blockIdx.x] = lds[SCAN_B - 1];
}

__global__ void scan_phaseB(int* blocksums, int nb) {
    __shared__ int lds[SCAN_B];
    int tid = threadIdx.x;
    int v = (tid < nb) ? blocksums[tid] : 0;
    lds[tid] = v;
    __syncthreads();
    for (int off = 1; off < SCAN_B; off <<= 1) {
        int t = (tid >= off) ? lds[tid - off] : 0;
        __syncthreads();
        lds[tid] += t;
        __syncthreads();
    }
    if (tid < nb) blocksums[tid] = lds[tid] - v;
}

__global__ void scan_phaseC(int* __restrict__ offs, const int* __restrict__ blocksums,
                            int* __restrict__ cursor, int n, int E) {
    int i = blockIdx.x * blockDim.x + threadIdx.x;
    if (i < n) {
        int o = offs[i] + blocksums[i / SCAN_B];
        offs[i] = o;
        cursor[i] = o;
    } else if (i == n) {
        offs[n] = E;
    }
}

// ---------------- fill: atomic-free (rank) and fallback (cursor) ----------------
__global__ void fill_rank_kernel(const int* __restrict__ src, const int* __restrict__ dst,
                                 const int* __restrict__ rank, const int* __restrict__ offs,
                                 int* __restrict__ ssort, int E) {
    int e = blockIdx.x * blockDim.x + threadIdx.x;
    if (e < E) ssort[offs[dst[e]] + rank[e]] = src[e];
}

__global__ void fill_cursor_kernel(const int* __restrict__ src, const int* __restrict__ dst,
                                   int* __restrict__ cursor, int* __restrict__ ssort, int E) {
    int e = blockIdx.x * blockDim.x + threadIdx.x;
    if (e < E) {
        int pos = atomicAdd(&cursor[dst[e]], 1);
        ssort[pos] = src[e];
    }
}

// ------- layer1 tail: b1 + relu + compact dense2 (h@W2 -> p) -------
__device__ __forceinline__ void layer1_tail(float acc, int lane, int node,
                                            const float* __restrict__ b1,
                                            const float* __restrict__ W2,
                                            float* __restrict__ p)
{
    float h = fmaxf(acc + b1[lane], 0.f);
    int j = lane & 15, ks = lane >> 4;
    float pp = 0.f;
#pragma unroll
    for (int i = 0; i < 16; ++i) {
        int kk = ks * 16 + i;
        float hk = __shfl(h, kk, 64);          // broadcast h[kk] from lane kk
        pp = fmaf(hk, W2[kk * 16 + j], pp);
    }
    pp += __shfl_xor(pp, 16, 64);
    pp += __shfl_xor(pp, 32, 64);
    if (ks == 0) p[(size_t)node * 16 + j] = pp;
}

// ---------- layer1: gather fW1 rows, float2/lane, 2 edges per load instr ----------
__global__ __launch_bounds__(256) void layer1_f32_kernel(
    const float2* __restrict__ fW1_2, const int* __restrict__ offs,
    const int* __restrict__ ssort, const float* __restrict__ b1,
    const float* __restrict__ W2, float* __restrict__ p, int n_nodes)
{
    int lane = threadIdx.x & 63;
    int w = threadIdx.x >> 6;
    int node = blockIdx.x * 4 + w;
    if (node >= n_nodes) return;            // no barriers below
    int beg = offs[node], end = offs[node + 1];
    int half = lane >> 5;                   // which edge of the pair
    int sl = lane & 31;                     // col pair -> cols 2sl, 2sl+1
    float ax = 0.f, ay = 0.f;
    int k = beg + half;
    for (; k + 6 < end; k += 8) {           // 8 edges in flight per wave
        int s0 = ssort[k], s1 = ssort[k + 2], s2 = ssort[k + 4], s3 = ssort[k + 6];
        float2 v0 = fW1_2[(size_t)s0 * 32 + sl];
        float2 v1 = fW1_2[(size_t)s1 * 32 + sl];
        float2 v2 = fW1_2[(size_t)s2 * 32 + sl];
        float2 v3 = fW1_2[(size_t)s3 * 32 + sl];
        ax += (v0.x + v1.x) + (v2.x + v3.x);
        ay += (v0.y + v1.y) + (v2.y + v3.y);
    }
    for (; k < end; k += 2) {
        float2 v = fW1_2[(size_t)ssort[k] * 32 + sl];
        ax += v.x;
        ay += v.y;
    }
    ax += __shfl_xor(ax, 32, 64);
    ay += __shfl_xor(ay, 32, 64);
    // redistribute (col-pair layout on 32 lanes) -> one col per lane
    float am = __shfl(ax, lane >> 1, 64);
    float bm = __shfl(ay, lane >> 1, 64);
    float acc = (lane & 1) ? bm : am;
    layer1_tail(acc, lane, node, b1, W2, p);
}

// ---------- layer2: wave/node, float2 per lane, 8 edges per load instr ----------
__global__ __launch_bounds__(256) void layer2_kernel(
    const float2* __restrict__ p2, const int* __restrict__ offs,
    const int* __restrict__ ssort, const float* __restrict__ b2,
    float* __restrict__ out, int n_nodes)
{
    int lane = threadIdx.x & 63;
    int w = threadIdx.x >> 6;
    int node = blockIdx.x * 4 + w;
    if (node >= n_nodes) return;
    int slot = lane >> 3;   // edge slot 0..7
    int cp = lane & 7;      // column pair -> cols 2cp, 2cp+1
    int beg = offs[node], end = offs[node + 1];
    float ax = 0.f, ay = 0.f;
    int k = beg + slot;
    for (; k + 8 < end; k += 16) {      // 16 edges in flight
        int s0 = ssort[k], s1 = ssort[k + 8];
        float2 v0 = p2[(size_t)s0 * 8 + cp];
        float2 v1 = p2[(size_t)s1 * 8 + cp];
        ax += v0.x + v1.x;
        ay += v0.y + v1.y;
    }
    for (; k < end; k += 8) {
        float2 v = p2[(size_t)ssort[k] * 8 + cp];
        ax += v.x;
        ay += v.y;
    }
    ax += __shfl_xor(ax, 8, 64);  ay += __shfl_xor(ay, 8, 64);
    ax += __shfl_xor(ax, 16, 64); ay += __shfl_xor(ay, 16, 64);
    ax += __shfl_xor(ax, 32, 64); ay += __shfl_xor(ay, 32, 64);
    float2 bb = ((const float2*)b2)[cp];
    float vx = ax + bb.x, vy = ay + bb.y;
    float m = fmaxf(vx, vy);
    m = fmaxf(m, __shfl_xor(m, 1, 64));
    m = fmaxf(m, __shfl_xor(m, 2, 64));
    m = fmaxf(m, __shfl_xor(m, 4, 64));
    float ex = __expf(vx - m), ey = __expf(vy - m);
    float s = ex + ey;
    s += __shfl_xor(s, 1, 64);
    s += __shfl_xor(s, 2, 64);
    s += __shfl_xor(s, 4, 64);
    if (slot == 0) {
        float inv = 1.f / s;
        float2 o; o.x = ex * inv; o.y = ey * inv;
        ((float2*)out)[(size_t)node * 8 + cp] = o;
    }
}

extern "C" void kernel_launch(void* const* d_in, const int* in_sizes, int n_in,
                              void* d_out, int out_size, void* d_ws, size_t ws_size,
                              hipStream_t stream) {
    const float* feat = (const float*)d_in[0];
    const float* W1   = (const float*)d_in[1];
    const float* b1   = (const float*)d_in[2];
    const float* W2   = (const float*)d_in[3];
    const float* b2   = (const float*)d_in[4];
    const int*   src  = (const int*)d_in[5];
    const int*   dst  = (const int*)d_in[6];

    int N = in_sizes[0] / 64;
    int E = in_sizes[5];

    // layout: p[16N] | fW1[64N] | counts[N] | offs[N+1] | cursor[N] | bsums | ssort[E] | rank[E]?
    float* p      = (float*)d_ws;
    float* fW1    = p + (size_t)N * 16;
    int*   counts = (int*)(fW1 + (size_t)N * 64);
    int*   offs   = counts + N;
    int*   cursor = offs + N + 1;
    int*   bsums  = cursor + N;
    int*   ssort  = bsums + SCAN_B;
    int*   rank   = ssort + E;
    size_t need_rank = (size_t)(rank + E - (int*)d_ws) * sizeof(int);
    bool use_rank = ws_size >= need_rank;
    float* out = (float*)d_out;

    int nb = (N + SCAN_B - 1) / SCAN_B;
    int histBlocks = (E + 255) / 256;

    hipMemsetAsync(counts, 0, (size_t)N * sizeof(int), stream);

    prep_kernel<<<FW1B + histBlocks, 256, 0, stream>>>(
        feat, W1, fW1, dst, counts, use_rank ? rank : nullptr, N, E);

    scan_phaseA<<<nb, SCAN_B, 0, stream>>>(counts, offs, bsums, N);
    scan_phaseB<<<1, SCAN_B, 0, stream>>>(bsums, nb);
    scan_phaseC<<<(N + 1 + 255) / 256, 256, 0, stream>>>(offs, bsums, cursor, N, E);

    if (use_rank) {
        fill_rank_kernel<<<(E + 255) / 256, 256, 0, stream>>>(src, dst, rank, offs, ssort, E);
    } else {
        fill_cursor_kernel<<<(E + 255) / 256, 256, 0, stream>>>(src, dst, cursor, ssort, E);
    }

    layer1_f32_kernel<<<(N + 3) / 4, 256, 0, stream>>>((const float2*)fW1, offs, ssort, b1, W2, p, N);
    layer2_kernel<<<(N + 3) / 4, 256, 0, stream>>>((const float2*)p, offs, ssort, b2, out, N);
}